// Round 1
// baseline (317.659 us; speedup 1.0000x reference)
//
#include <hip/hip_runtime.h>
#include <hip/hip_bf16.h>

// ---------------------------------------------------------------------------
// Fused MHA forward on MI355X (gfx950), bf16 MFMA pipeline:
//   1) cast f32->bf16 (activations, weights)
//   2) fused QKV projection GEMM (B^T layout), epilogue -> head layouts
//   3) flash attention (online softmax), 64 q-rows/block, 64-wide KV tiles
//   4) output projection GEMM, fp32 + bias epilogue
// ---------------------------------------------------------------------------

typedef __attribute__((ext_vector_type(8))) short short8;   // 8 x bf16 bits
typedef __attribute__((ext_vector_type(4))) float f32x4;

static constexpr int D_MODEL = 1024;
static constexpr int NHEAD   = 16;
static constexpr int DK      = 64;
static constexpr int SEQ     = 2048;
static constexpr int BATCH   = 2;
static constexpr int MTOT    = BATCH * SEQ;   // 4096

#define DEVINL __device__ __forceinline__

DEVINL unsigned short f2bf(float f) {
    __hip_bfloat16 h = __float2bfloat16(f);   // RNE
    return *reinterpret_cast<unsigned short*>(&h);
}

// ---------------------------------------------------------------------------
// Cast kernel: up to 4 tensors of identical length, grid.y selects.
// 8 floats / thread, vectorized 2x float4 in, 1x 16B out.
// ---------------------------------------------------------------------------
__global__ __launch_bounds__(256) void cast_f32_bf16(
    const float* __restrict__ s0, const float* __restrict__ s1,
    const float* __restrict__ s2, const float* __restrict__ s3,
    unsigned short* __restrict__ d0, unsigned short* __restrict__ d1,
    unsigned short* __restrict__ d2, unsigned short* __restrict__ d3,
    int n)
{
    const float* s; unsigned short* d;
    switch (blockIdx.y) {
        case 0:  s = s0; d = d0; break;
        case 1:  s = s1; d = d1; break;
        case 2:  s = s2; d = d2; break;
        default: s = s3; d = d3; break;
    }
    int i = (blockIdx.x * 256 + threadIdx.x) * 8;
    if (i + 8 > n) return;
    float4 v0 = *reinterpret_cast<const float4*>(s + i);
    float4 v1 = *reinterpret_cast<const float4*>(s + i + 4);
    union { unsigned short u[8]; short8 v; } o;
    o.u[0] = f2bf(v0.x); o.u[1] = f2bf(v0.y); o.u[2] = f2bf(v0.z); o.u[3] = f2bf(v0.w);
    o.u[4] = f2bf(v1.x); o.u[5] = f2bf(v1.y); o.u[6] = f2bf(v1.z); o.u[7] = f2bf(v1.w);
    *reinterpret_cast<short8*>(d + i) = o.v;
}

// ---------------------------------------------------------------------------
// GEMM core: C[m,n] = sum_k A[m,k] * W[n,k] + bias[n]   (both row-major, K=1024)
// 128x128 tile, BK=32, 4 waves (2x2), 16x16x32 bf16 MFMA, global_load_lds(16B).
// MODE 0: out bf16, head layout  [B,H,S,DK]   (q,k projections)
// MODE 1: out bf16, vT layout    [B,H,DK,S]   (v projection, pre-transposed)
// MODE 2: out f32,  row-major    [M,D_MODEL]  (final output)
// ---------------------------------------------------------------------------
template<int MODE>
DEVINL void gemm_core(const unsigned short* __restrict__ A,
                      const unsigned short* __restrict__ W,
                      const float* __restrict__ bias,
                      void* __restrict__ outp,
                      int m0, int n0,
                      unsigned short* a_lds, unsigned short* b_lds)
{
    constexpr int K = 1024;
    const int tid  = threadIdx.x;
    const int wave = tid >> 6, lane = tid & 63;
    const int wrow = (wave >> 1) * 64, wcol = (wave & 1) * 64;
    const int fr = lane & 15, fg = lane >> 4;

    f32x4 acc[4][4];
    #pragma unroll
    for (int i = 0; i < 4; ++i)
        #pragma unroll
        for (int j = 0; j < 4; ++j)
            acc[i][j] = (f32x4){0.f, 0.f, 0.f, 0.f};

    // staging: chunk c (16B) -> lds byte c*16; row=c>>2, k-elems (c&3)*8
    const int c0 = tid, c1 = tid + 256;
    const unsigned short* gA0 = A + (size_t)(m0 + (c0 >> 2)) * K + (c0 & 3) * 8;
    const unsigned short* gA1 = A + (size_t)(m0 + (c1 >> 2)) * K + (c1 & 3) * 8;
    const unsigned short* gB0 = W + (size_t)(n0 + (c0 >> 2)) * K + (c0 & 3) * 8;
    const unsigned short* gB1 = W + (size_t)(n0 + (c1 >> 2)) * K + (c1 & 3) * 8;
    char* aLb = (char*)a_lds + wave * 1024;   // wave-uniform base, HW adds lane*16
    char* bLb = (char*)b_lds + wave * 1024;

    const unsigned short* aF = a_lds + (wrow + fr) * 32 + fg * 8;
    const unsigned short* bF = b_lds + (wcol + fr) * 32 + fg * 8;

    for (int kt = 0; kt < K / 32; ++kt) {
        __syncthreads();   // previous iter's reads done before overwrite
        __builtin_amdgcn_global_load_lds(gA0 + kt * 32, aLb,        16, 0, 0);
        __builtin_amdgcn_global_load_lds(gA1 + kt * 32, aLb + 4096, 16, 0, 0);
        __builtin_amdgcn_global_load_lds(gB0 + kt * 32, bLb,        16, 0, 0);
        __builtin_amdgcn_global_load_lds(gB1 + kt * 32, bLb + 4096, 16, 0, 0);
        __syncthreads();   // implies vmcnt(0): staged data visible

        short8 af[4], bf[4];
        #pragma unroll
        for (int mt = 0; mt < 4; ++mt)
            af[mt] = *reinterpret_cast<const short8*>(aF + mt * 16 * 32);
        #pragma unroll
        for (int nt = 0; nt < 4; ++nt)
            bf[nt] = *reinterpret_cast<const short8*>(bF + nt * 16 * 32);
        #pragma unroll
        for (int mt = 0; mt < 4; ++mt)
            #pragma unroll
            for (int nt = 0; nt < 4; ++nt)
                acc[mt][nt] = __builtin_amdgcn_mfma_f32_16x16x32_bf16(
                    af[mt], bf[nt], acc[mt][nt], 0, 0, 0);
    }

    // epilogue: C/D layout col = lane&15, row = (lane>>4)*4 + r  [m89-verified]
    #pragma unroll
    for (int mt = 0; mt < 4; ++mt) {
        #pragma unroll
        for (int nt = 0; nt < 4; ++nt) {
            f32x4 v = acc[mt][nt];
            const int n = n0 + wcol + nt * 16 + fr;
            const float bi = bias[n];
            #pragma unroll
            for (int r = 0; r < 4; ++r) {
                const int m = m0 + wrow + mt * 16 + fg * 4 + r;
                const float val = v[r] + bi;
                if constexpr (MODE == 2) {
                    ((float*)outp)[(size_t)m * D_MODEL + n] = val;
                } else {
                    const int b = m >> 11, s = m & 2047;
                    const int h = n >> 6,  d = n & 63;
                    size_t off;
                    if constexpr (MODE == 0)
                        off = ((size_t)(b * NHEAD + h) * SEQ + s) * DK + d;
                    else
                        off = ((size_t)(b * NHEAD + h) * DK + d) * SEQ + s;
                    ((unsigned short*)outp)[off] = f2bf(val);
                }
            }
        }
    }
}

__global__ __launch_bounds__(256) void qkv_gemm(
    const unsigned short* __restrict__ Qb, const unsigned short* __restrict__ Kb,
    const unsigned short* __restrict__ Vb,
    const unsigned short* __restrict__ Wq, const unsigned short* __restrict__ Wk,
    const unsigned short* __restrict__ Wv,
    const float* __restrict__ bq, const float* __restrict__ bk,
    const float* __restrict__ bv,
    unsigned short* __restrict__ qh, unsigned short* __restrict__ kh,
    unsigned short* __restrict__ vT)
{
    __shared__ unsigned short a_lds[128 * 32];
    __shared__ unsigned short b_lds[128 * 32];
    const int sel = blockIdx.y >> 3;
    const int n0  = (blockIdx.y & 7) * 128;
    const int m0  = blockIdx.x * 128;
    if (sel == 0)      gemm_core<0>(Qb, Wq, bq, qh, m0, n0, a_lds, b_lds);
    else if (sel == 1) gemm_core<0>(Kb, Wk, bk, kh, m0, n0, a_lds, b_lds);
    else               gemm_core<1>(Vb, Wv, bv, vT, m0, n0, a_lds, b_lds);
}

__global__ __launch_bounds__(256) void oproj_gemm(
    const unsigned short* __restrict__ ctx, const unsigned short* __restrict__ Wo,
    const float* __restrict__ bo, float* __restrict__ out)
{
    __shared__ unsigned short a_lds[128 * 32];
    __shared__ unsigned short b_lds[128 * 32];
    gemm_core<2>(ctx, Wo, bo, out, blockIdx.x * 128, blockIdx.y * 128, a_lds, b_lds);
}

// ---------------------------------------------------------------------------
// Flash attention: grid (S/64, H, B), 256 threads (4 waves).
// Wave w owns q-rows [blk*64 + w*16, +16). KV tiles of 64.
// K tile LDS [64 kv][64 d], V^T tile LDS [64 d][64 kv], both padded to 72
// (144 B row stride: 16B-aligned, 2-way banks within a 16-lane group).
// ---------------------------------------------------------------------------
__global__ __launch_bounds__(256) void attn_fwd(
    const unsigned short* __restrict__ qh,
    const unsigned short* __restrict__ kh,
    const unsigned short* __restrict__ vT,
    unsigned short* __restrict__ ctx)
{
    __shared__ unsigned short k_lds[64][72];
    __shared__ unsigned short v_lds[64][72];
    __shared__ unsigned short p_lds[4][16][72];

    const int tid  = threadIdx.x;
    const int wave = tid >> 6, lane = tid & 63;
    const int fr = lane & 15, fg = lane >> 4;
    const int h = blockIdx.y, b = blockIdx.z;
    const int q0 = blockIdx.x * 64 + wave * 16;

    const size_t headoff = (size_t)(b * NHEAD + h) * SEQ * DK;
    const unsigned short* qbase = qh + headoff;
    const unsigned short* kbase = kh + headoff;
    const unsigned short* vbase = vT + headoff;   // [DK][SEQ]

    // Q fragments, held for the whole block: A-frag row = fr, k = fg*8
    short8 qf[2];
    #pragma unroll
    for (int ks = 0; ks < 2; ++ks)
        qf[ks] = *reinterpret_cast<const short8*>(
            qbase + (size_t)(q0 + fr) * DK + ks * 32 + fg * 8);

    f32x4 oacc[4];
    #pragma unroll
    for (int i = 0; i < 4; ++i) oacc[i] = (f32x4){0.f, 0.f, 0.f, 0.f};
    float mrun[4], lrun[4];
    #pragma unroll
    for (int r = 0; r < 4; ++r) { mrun[r] = -1e30f; lrun[r] = 0.f; }

    constexpr float SCL = 0.125f * 1.44269504088896340736f; // 1/sqrt(64) * log2(e)

    const int srow = tid >> 2;           // staging row 0..63
    const int schk = (tid & 3) * 16;     // staging elem offset 0/16/32/48

    for (int kt = 0; kt < SEQ / 64; ++kt) {
        const int kv0 = kt * 64;
        __syncthreads();   // prior tile's LDS reads complete
        {
            const short8* gk = reinterpret_cast<const short8*>(
                kbase + (size_t)(kv0 + srow) * DK + schk);
            *reinterpret_cast<short8*>(&k_lds[srow][schk])     = gk[0];
            *reinterpret_cast<short8*>(&k_lds[srow][schk + 8]) = gk[1];
            const short8* gv = reinterpret_cast<const short8*>(
                vbase + (size_t)srow * SEQ + kv0 + schk);
            *reinterpret_cast<short8*>(&v_lds[srow][schk])     = gv[0];
            *reinterpret_cast<short8*>(&v_lds[srow][schk + 8]) = gv[1];
        }
        __syncthreads();

        // S = q . k^T  (16q x 64kv), acc over d: 2 k-steps
        f32x4 sacc[4];
        #pragma unroll
        for (int i = 0; i < 4; ++i) sacc[i] = (f32x4){0.f, 0.f, 0.f, 0.f};
        #pragma unroll
        for (int ks = 0; ks < 2; ++ks) {
            #pragma unroll
            for (int nt = 0; nt < 4; ++nt) {
                short8 kf = *reinterpret_cast<const short8*>(
                    &k_lds[nt * 16 + fr][ks * 32 + fg * 8]);
                sacc[nt] = __builtin_amdgcn_mfma_f32_16x16x32_bf16(
                    qf[ks], kf, sacc[nt], 0, 0, 0);
            }
        }

        // online softmax (log2 domain); S row = fg*4+r, col = nt*16+fr
        #pragma unroll
        for (int nt = 0; nt < 4; ++nt)
            #pragma unroll
            for (int r = 0; r < 4; ++r)
                sacc[nt][r] *= SCL;

        #pragma unroll
        for (int r = 0; r < 4; ++r) {
            float mx = fmaxf(fmaxf(sacc[0][r], sacc[1][r]),
                             fmaxf(sacc[2][r], sacc[3][r]));
            mx = fmaxf(mx, __shfl_xor(mx, 1));
            mx = fmaxf(mx, __shfl_xor(mx, 2));
            mx = fmaxf(mx, __shfl_xor(mx, 4));
            mx = fmaxf(mx, __shfl_xor(mx, 8));
            const float mn = fmaxf(mrun[r], mx);
            const float alpha = exp2f(mrun[r] - mn);
            mrun[r] = mn;
            float rs = 0.f;
            #pragma unroll
            for (int nt = 0; nt < 4; ++nt) {
                float p = exp2f(sacc[nt][r] - mn);
                sacc[nt][r] = p;
                rs += p;
            }
            rs += __shfl_xor(rs, 1);
            rs += __shfl_xor(rs, 2);
            rs += __shfl_xor(rs, 4);
            rs += __shfl_xor(rs, 8);
            lrun[r] = lrun[r] * alpha + rs;
            #pragma unroll
            for (int ntd = 0; ntd < 4; ++ntd)
                oacc[ntd][r] *= alpha;
        }

        // P -> LDS (re-layout for A-fragment), then PV
        #pragma unroll
        for (int nt = 0; nt < 4; ++nt)
            #pragma unroll
            for (int r = 0; r < 4; ++r)
                p_lds[wave][fg * 4 + r][nt * 16 + fr] = f2bf(sacc[nt][r]);
        __syncthreads();

        #pragma unroll
        for (int ks = 0; ks < 2; ++ks) {
            short8 pf = *reinterpret_cast<const short8*>(
                &p_lds[wave][fr][ks * 32 + fg * 8]);
            #pragma unroll
            for (int ntd = 0; ntd < 4; ++ntd) {
                short8 vf = *reinterpret_cast<const short8*>(
                    &v_lds[ntd * 16 + fr][ks * 32 + fg * 8]);
                oacc[ntd] = __builtin_amdgcn_mfma_f32_16x16x32_bf16(
                    pf, vf, oacc[ntd], 0, 0, 0);
            }
        }
    }

    // finalize: O /= l; store ctx bf16 [B,S,D_MODEL]
    float inv[4];
    #pragma unroll
    for (int r = 0; r < 4; ++r) inv[r] = 1.f / lrun[r];
    #pragma unroll
    for (int ntd = 0; ntd < 4; ++ntd)
        #pragma unroll
        for (int r = 0; r < 4; ++r) {
            const int qg = q0 + fg * 4 + r;
            const size_t off = ((size_t)(b * SEQ + qg)) * D_MODEL
                             + h * DK + ntd * 16 + fr;
            ctx[off] = f2bf(oacc[ntd][r] * inv[r]);
        }
}

// ---------------------------------------------------------------------------
extern "C" void kernel_launch(void* const* d_in, const int* in_sizes, int n_in,
                              void* d_out, int out_size, void* d_ws, size_t ws_size,
                              hipStream_t stream)
{
    const float* Q  = (const float*)d_in[0];
    const float* K  = (const float*)d_in[1];
    const float* V  = (const float*)d_in[2];
    const float* Wq = (const float*)d_in[3];
    const float* bq = (const float*)d_in[4];
    const float* Wk = (const float*)d_in[5];
    const float* bk = (const float*)d_in[6];
    const float* Wv = (const float*)d_in[7];
    const float* bv = (const float*)d_in[8];
    const float* Wo = (const float*)d_in[9];
    const float* bo = (const float*)d_in[10];

    // workspace layout (bytes); total 64 MiB
    char* ws = (char*)d_ws;
    const size_t SZ_ACT = (size_t)MTOT * D_MODEL * 2;      // 8 MiB
    const size_t SZ_W   = (size_t)D_MODEL * D_MODEL * 2;   // 2 MiB
    unsigned short* Qb  = (unsigned short*)(ws);
    unsigned short* Kb  = (unsigned short*)(ws + SZ_ACT);
    unsigned short* Vb  = (unsigned short*)(ws + 2 * SZ_ACT);
    unsigned short* Wqb = (unsigned short*)(ws + 3 * SZ_ACT);
    unsigned short* Wkb = (unsigned short*)(ws + 3 * SZ_ACT + SZ_W);
    unsigned short* Wvb = (unsigned short*)(ws + 3 * SZ_ACT + 2 * SZ_W);
    unsigned short* Wob = (unsigned short*)(ws + 3 * SZ_ACT + 3 * SZ_W);
    unsigned short* qhd = (unsigned short*)(ws + 3 * SZ_ACT + 4 * SZ_W);
    unsigned short* khd = (unsigned short*)(ws + 4 * SZ_ACT + 4 * SZ_W);
    unsigned short* vTd = (unsigned short*)(ws + 5 * SZ_ACT + 4 * SZ_W);
    unsigned short* ctx = (unsigned short*)(ws + 6 * SZ_ACT + 4 * SZ_W);

    const int nAct = MTOT * D_MODEL;        // 4194304
    const int nW   = D_MODEL * D_MODEL;     // 1048576

    cast_f32_bf16<<<dim3(nAct / (256 * 8), 3), 256, 0, stream>>>(
        Q, K, V, nullptr, Qb, Kb, Vb, nullptr, nAct);
    cast_f32_bf16<<<dim3(nW / (256 * 8), 4), 256, 0, stream>>>(
        Wq, Wk, Wv, Wo, Wqb, Wkb, Wvb, Wob, nW);

    qkv_gemm<<<dim3(MTOT / 128, 24), 256, 0, stream>>>(
        Qb, Kb, Vb, Wqb, Wkb, Wvb, bq, bk, bv, qhd, khd, vTd);

    attn_fwd<<<dim3(SEQ / 64, NHEAD, BATCH), 256, 0, stream>>>(
        qhd, khd, vTd, ctx);

    oproj_gemm<<<dim3(MTOT / 128, D_MODEL / 128), 256, 0, stream>>>(
        ctx, Wob, bo, (float*)d_out);
}

// Round 2
// 249.810 us; speedup vs baseline: 1.2716x; 1.2716x over previous
//
#include <hip/hip_runtime.h>
#include <hip/hip_bf16.h>

// ---------------------------------------------------------------------------
// Fused MHA forward on MI355X (gfx950), bf16 MFMA pipeline:
//   1) cast f32->bf16 (activations, weights)
//   2) fused QKV projection GEMM (B^T layout), epilogue -> head layouts
//   3) flash attention: XOR-swizzled LDS, global_load_lds staging with
//      pre-swizzled source, defer-max online softmax (THR=8, log2 domain)
//   4) output projection GEMM, fp32 + bias epilogue
// ---------------------------------------------------------------------------

typedef __attribute__((ext_vector_type(8))) short short8;   // 8 x bf16 bits
typedef __attribute__((ext_vector_type(4))) float f32x4;
typedef __attribute__((ext_vector_type(4))) unsigned short us4;

static constexpr int D_MODEL = 1024;
static constexpr int NHEAD   = 16;
static constexpr int DK      = 64;
static constexpr int SEQ     = 2048;
static constexpr int BATCH   = 2;
static constexpr int MTOT    = BATCH * SEQ;   // 4096

#define DEVINL __device__ __forceinline__

DEVINL unsigned short f2bf(float f) {
    __hip_bfloat16 h = __float2bfloat16(f);   // RNE
    return *reinterpret_cast<unsigned short*>(&h);
}

// ---------------------------------------------------------------------------
// Cast kernel: up to 4 tensors of identical length, grid.y selects.
// ---------------------------------------------------------------------------
__global__ __launch_bounds__(256) void cast_f32_bf16(
    const float* __restrict__ s0, const float* __restrict__ s1,
    const float* __restrict__ s2, const float* __restrict__ s3,
    unsigned short* __restrict__ d0, unsigned short* __restrict__ d1,
    unsigned short* __restrict__ d2, unsigned short* __restrict__ d3,
    int n)
{
    const float* s; unsigned short* d;
    switch (blockIdx.y) {
        case 0:  s = s0; d = d0; break;
        case 1:  s = s1; d = d1; break;
        case 2:  s = s2; d = d2; break;
        default: s = s3; d = d3; break;
    }
    int i = (blockIdx.x * 256 + threadIdx.x) * 8;
    if (i + 8 > n) return;
    float4 v0 = *reinterpret_cast<const float4*>(s + i);
    float4 v1 = *reinterpret_cast<const float4*>(s + i + 4);
    union { unsigned short u[8]; short8 v; } o;
    o.u[0] = f2bf(v0.x); o.u[1] = f2bf(v0.y); o.u[2] = f2bf(v0.z); o.u[3] = f2bf(v0.w);
    o.u[4] = f2bf(v1.x); o.u[5] = f2bf(v1.y); o.u[6] = f2bf(v1.z); o.u[7] = f2bf(v1.w);
    *reinterpret_cast<short8*>(d + i) = o.v;
}

// ---------------------------------------------------------------------------
// GEMM core: C[m,n] = sum_k A[m,k] * W[n,k] + bias[n]   (row-major, K=1024)
// 128x128 tile, BK=32, 4 waves (2x2), 16x16x32 bf16 MFMA, global_load_lds(16B).
// MODE 0: out bf16, head layout  [B,H,S,DK]   (q,k projections)
// MODE 1: out bf16, vT layout    [B,H,DK,S]   (v projection, pre-transposed)
// MODE 2: out f32,  row-major    [M,D_MODEL]  (final output)
// ---------------------------------------------------------------------------
template<int MODE>
DEVINL void gemm_core(const unsigned short* __restrict__ A,
                      const unsigned short* __restrict__ W,
                      const float* __restrict__ bias,
                      void* __restrict__ outp,
                      int m0, int n0,
                      unsigned short* a_lds, unsigned short* b_lds)
{
    constexpr int K = 1024;
    const int tid  = threadIdx.x;
    const int wave = tid >> 6, lane = tid & 63;
    const int wrow = (wave >> 1) * 64, wcol = (wave & 1) * 64;
    const int fr = lane & 15, fg = lane >> 4;

    f32x4 acc[4][4];
    #pragma unroll
    for (int i = 0; i < 4; ++i)
        #pragma unroll
        for (int j = 0; j < 4; ++j)
            acc[i][j] = (f32x4){0.f, 0.f, 0.f, 0.f};

    const int c0 = tid, c1 = tid + 256;
    const unsigned short* gA0 = A + (size_t)(m0 + (c0 >> 2)) * K + (c0 & 3) * 8;
    const unsigned short* gA1 = A + (size_t)(m0 + (c1 >> 2)) * K + (c1 & 3) * 8;
    const unsigned short* gB0 = W + (size_t)(n0 + (c0 >> 2)) * K + (c0 & 3) * 8;
    const unsigned short* gB1 = W + (size_t)(n0 + (c1 >> 2)) * K + (c1 & 3) * 8;
    char* aLb = (char*)a_lds + wave * 1024;
    char* bLb = (char*)b_lds + wave * 1024;

    const unsigned short* aF = a_lds + (wrow + fr) * 32 + fg * 8;
    const unsigned short* bF = b_lds + (wcol + fr) * 32 + fg * 8;

    for (int kt = 0; kt < K / 32; ++kt) {
        __syncthreads();
        __builtin_amdgcn_global_load_lds(gA0 + kt * 32, aLb,        16, 0, 0);
        __builtin_amdgcn_global_load_lds(gA1 + kt * 32, aLb + 4096, 16, 0, 0);
        __builtin_amdgcn_global_load_lds(gB0 + kt * 32, bLb,        16, 0, 0);
        __builtin_amdgcn_global_load_lds(gB1 + kt * 32, bLb + 4096, 16, 0, 0);
        __syncthreads();

        short8 af[4], bf[4];
        #pragma unroll
        for (int mt = 0; mt < 4; ++mt)
            af[mt] = *reinterpret_cast<const short8*>(aF + mt * 16 * 32);
        #pragma unroll
        for (int nt = 0; nt < 4; ++nt)
            bf[nt] = *reinterpret_cast<const short8*>(bF + nt * 16 * 32);
        #pragma unroll
        for (int mt = 0; mt < 4; ++mt)
            #pragma unroll
            for (int nt = 0; nt < 4; ++nt)
                acc[mt][nt] = __builtin_amdgcn_mfma_f32_16x16x32_bf16(
                    af[mt], bf[nt], acc[mt][nt], 0, 0, 0);
    }

    // epilogue: C/D layout col = lane&15 (=n), row = (lane>>4)*4 + r (=m)
    #pragma unroll
    for (int mt = 0; mt < 4; ++mt) {
        #pragma unroll
        for (int nt = 0; nt < 4; ++nt) {
            f32x4 v = acc[mt][nt];
            const int n = n0 + wcol + nt * 16 + fr;
            const float bi = bias[n];
            if constexpr (MODE == 2) {
                #pragma unroll
                for (int r = 0; r < 4; ++r) {
                    const int m = m0 + wrow + mt * 16 + fg * 4 + r;
                    ((float*)outp)[(size_t)m * D_MODEL + n] = v[r] + bi;
                }
            } else if constexpr (MODE == 0) {
                #pragma unroll
                for (int r = 0; r < 4; ++r) {
                    const int m = m0 + wrow + mt * 16 + fg * 4 + r;
                    const int b = m >> 11, s = m & 2047;
                    const int h = n >> 6,  d = n & 63;
                    ((unsigned short*)outp)[((size_t)(b * NHEAD + h) * SEQ + s) * DK + d]
                        = f2bf(v[r] + bi);
                }
            } else {   // MODE 1: vT [B,H,DK,S], pack 4 consecutive s into 8B store
                const int sbase = m0 + wrow + mt * 16 + fg * 4;
                const int b = sbase >> 11, s = sbase & 2047;
                const int h = n >> 6, d = n & 63;
                us4 pk;
                #pragma unroll
                for (int r = 0; r < 4; ++r)
                    pk[r] = f2bf(v[r] + bi);
                *reinterpret_cast<us4*>(
                    (unsigned short*)outp
                    + ((size_t)(b * NHEAD + h) * DK + d) * SEQ + s) = pk;
            }
        }
    }
}

__global__ __launch_bounds__(256) void qkv_gemm(
    const unsigned short* __restrict__ Qb, const unsigned short* __restrict__ Kb,
    const unsigned short* __restrict__ Vb,
    const unsigned short* __restrict__ Wq, const unsigned short* __restrict__ Wk,
    const unsigned short* __restrict__ Wv,
    const float* __restrict__ bq, const float* __restrict__ bk,
    const float* __restrict__ bv,
    unsigned short* __restrict__ qh, unsigned short* __restrict__ kh,
    unsigned short* __restrict__ vT)
{
    __shared__ unsigned short a_lds[128 * 32];
    __shared__ unsigned short b_lds[128 * 32];
    const int sel = blockIdx.y >> 3;
    const int n0  = (blockIdx.y & 7) * 128;
    const int m0  = blockIdx.x * 128;
    if (sel == 0)      gemm_core<0>(Qb, Wq, bq, qh, m0, n0, a_lds, b_lds);
    else if (sel == 1) gemm_core<0>(Kb, Wk, bk, kh, m0, n0, a_lds, b_lds);
    else               gemm_core<1>(Vb, Wv, bv, vT, m0, n0, a_lds, b_lds);
}

__global__ __launch_bounds__(256) void oproj_gemm(
    const unsigned short* __restrict__ ctx, const unsigned short* __restrict__ Wo,
    const float* __restrict__ bo, float* __restrict__ out)
{
    __shared__ unsigned short a_lds[128 * 32];
    __shared__ unsigned short b_lds[128 * 32];
    gemm_core<2>(ctx, Wo, bo, out, blockIdx.x * 128, blockIdx.y * 128, a_lds, b_lds);
}

// ---------------------------------------------------------------------------
// Flash attention: grid (S/64, H, B), 256 threads (4 waves).
// Wave w owns q-rows [blk*64 + w*16, +16). KV tiles of 64.
// K tile [64 kv][64 d], V^T tile [64 d][64 kv], P tile per-wave [16 q][64 kv]
// -- all XOR-swizzled: byte_in_row ^= (row&7)<<4  (128 B rows, no pad).
// K/V staged via global_load_lds with pre-swizzled SOURCE (linear LDS dest).
// Online softmax: defer-max (THR=8 log2), per-lane partial l, reduce at end.
// ---------------------------------------------------------------------------
__global__ __launch_bounds__(256) void attn_fwd(
    const unsigned short* __restrict__ qh,
    const unsigned short* __restrict__ kh,
    const unsigned short* __restrict__ vT,
    unsigned short* __restrict__ ctx)
{
    __shared__ unsigned short k_lds[64 * 64];     // 8 KiB
    __shared__ unsigned short v_lds[64 * 64];     // 8 KiB
    __shared__ unsigned short p_lds[4][16 * 64];  // 8 KiB (per-wave private)

    const int tid  = threadIdx.x;
    const int wave = tid >> 6, lane = tid & 63;
    const int fr = lane & 15, fg = lane >> 4;
    const int swz = (fr & 7) << 4;                // row-XOR for frag reads
    const int h = blockIdx.y, b = blockIdx.z;
    const int q0 = blockIdx.x * 64 + wave * 16;

    const size_t headoff = (size_t)(b * NHEAD + h) * SEQ * DK;
    const unsigned short* qbase = qh + headoff;
    const unsigned short* kbase = kh + headoff;
    const unsigned short* vbase = vT + headoff;   // [DK][SEQ]

    // Q fragments (A-frag: row q=fr, k-chunk fg*8), held in regs all kernel
    short8 qf[2];
    #pragma unroll
    for (int ks = 0; ks < 2; ++ks)
        qf[ks] = *reinterpret_cast<const short8*>(
            qbase + (size_t)(q0 + fr) * DK + ks * 32 + fg * 8);

    // staging addresses: chunk c -> lds byte c*16 (linear); row=c>>3, slot=c&7
    // LDS slot s holds global col-slot s^(row&7)  (inverse-swizzled source)
    const int c0 = tid, c1 = 256 + tid;
    const int r0 = c0 >> 3, s0 = (c0 & 7) ^ (r0 & 7);
    const int r1 = c1 >> 3, s1 = (c1 & 7) ^ (r1 & 7);
    const unsigned short* gk0 = kbase + (size_t)r0 * DK + s0 * 8;
    const unsigned short* gk1 = kbase + (size_t)r1 * DK + s1 * 8;
    const unsigned short* gv0 = vbase + (size_t)r0 * SEQ + s0 * 8;
    const unsigned short* gv1 = vbase + (size_t)r1 * SEQ + s1 * 8;
    char* kl0 = (char*)k_lds + wave * 1024;
    char* kl1 = (char*)k_lds + 4096 + wave * 1024;
    char* vl0 = (char*)v_lds + wave * 1024;
    char* vl1 = (char*)v_lds + 4096 + wave * 1024;
    char* pwr = (char*)p_lds[wave];
    const char* prd = (const char*)p_lds[wave] + fr * 128;

    f32x4 oacc[4];
    #pragma unroll
    for (int i = 0; i < 4; ++i) oacc[i] = (f32x4){0.f, 0.f, 0.f, 0.f};
    float mrun[4], lpart[4];
    #pragma unroll
    for (int r = 0; r < 4; ++r) { mrun[r] = -1e30f; lpart[r] = 0.f; }

    constexpr float SCL = 0.125f * 1.44269504088896340736f; // 1/sqrt(64)*log2e
    constexpr float THR = 8.0f;

    for (int kt = 0; kt < SEQ / 64; ++kt) {
        const int kv0 = kt * 64;
        __syncthreads();   // prior tile's frag reads retired
        __builtin_amdgcn_global_load_lds(gk0 + (size_t)kv0 * DK, kl0, 16, 0, 0);
        __builtin_amdgcn_global_load_lds(gk1 + (size_t)kv0 * DK, kl1, 16, 0, 0);
        __builtin_amdgcn_global_load_lds(gv0 + kv0,              vl0, 16, 0, 0);
        __builtin_amdgcn_global_load_lds(gv1 + kv0,              vl1, 16, 0, 0);
        __syncthreads();   // drains vmcnt: staged data visible

        // S = Q.K^T (16q x 64kv): D row q = fg*4+r, col kv = nt*16+fr
        f32x4 sacc[4];
        #pragma unroll
        for (int i = 0; i < 4; ++i) sacc[i] = (f32x4){0.f, 0.f, 0.f, 0.f};
        #pragma unroll
        for (int ks = 0; ks < 2; ++ks) {
            #pragma unroll
            for (int nt = 0; nt < 4; ++nt) {
                const int krow = nt * 16 + fr;   // krow&7 == fr&7
                short8 kf = *reinterpret_cast<const short8*>(
                    (const char*)k_lds + krow * 128 + ((ks * 64 + fg * 16) ^ swz));
                sacc[nt] = __builtin_amdgcn_mfma_f32_16x16x32_bf16(
                    qf[ks], kf, sacc[nt], 0, 0, 0);
            }
        }

        #pragma unroll
        for (int nt = 0; nt < 4; ++nt)
            #pragma unroll
            for (int r = 0; r < 4; ++r)
                sacc[nt][r] *= SCL;

        // defer-max: steady state has NO cross-lane ops
        float lmax[4];
        bool need = false;
        #pragma unroll
        for (int r = 0; r < 4; ++r) {
            lmax[r] = fmaxf(fmaxf(sacc[0][r], sacc[1][r]),
                            fmaxf(sacc[2][r], sacc[3][r]));
            need |= (lmax[r] > mrun[r] + THR);
        }
        if (__any(need)) {   // rescale path (first tile + rare growth)
            #pragma unroll
            for (int r = 0; r < 4; ++r) {
                float mx = fmaxf(lmax[r], mrun[r]);
                mx = fmaxf(mx, __shfl_xor(mx, 1));
                mx = fmaxf(mx, __shfl_xor(mx, 2));
                mx = fmaxf(mx, __shfl_xor(mx, 4));
                mx = fmaxf(mx, __shfl_xor(mx, 8));
                const float alpha = __builtin_amdgcn_exp2f(mrun[r] - mx);
                mrun[r] = mx;
                lpart[r] *= alpha;
                #pragma unroll
                for (int ntd = 0; ntd < 4; ++ntd)
                    oacc[ntd][r] *= alpha;
            }
        }

        // P = exp2(S - m), per-lane partial row sums
        #pragma unroll
        for (int r = 0; r < 4; ++r) {
            float rs = 0.f;
            #pragma unroll
            for (int nt = 0; nt < 4; ++nt) {
                const float p = __builtin_amdgcn_exp2f(sacc[nt][r] - mrun[r]);
                sacc[nt][r] = p;
                rs += p;
            }
            lpart[r] += rs;
        }

        // P -> wave-private LDS (swizzled), no barrier needed
        #pragma unroll
        for (int nt = 0; nt < 4; ++nt)
            #pragma unroll
            for (int r = 0; r < 4; ++r) {
                const int qrow = fg * 4 + r;
                *(unsigned short*)(pwr + qrow * 128
                    + ((nt * 32 + fr * 2) ^ ((qrow & 7) << 4)))
                    = f2bf(sacc[nt][r]);
            }

        // O += P.V^T : A=P rows q=fr, B=V^T rows d=fr, contract over kv
        #pragma unroll
        for (int ks = 0; ks < 2; ++ks) {
            short8 pf = *reinterpret_cast<const short8*>(
                prd + ((ks * 64 + fg * 16) ^ swz));
            #pragma unroll
            for (int ntd = 0; ntd < 4; ++ntd) {
                const int vrow = ntd * 16 + fr;
                short8 vf = *reinterpret_cast<const short8*>(
                    (const char*)v_lds + vrow * 128 + ((ks * 64 + fg * 16) ^ swz));
                oacc[ntd] = __builtin_amdgcn_mfma_f32_16x16x32_bf16(
                    pf, vf, oacc[ntd], 0, 0, 0);
            }
        }
    }

    // final: reduce per-lane l partials once, normalize, store bf16 ctx
    float inv[4];
    #pragma unroll
    for (int r = 0; r < 4; ++r) {
        float s = lpart[r];
        s += __shfl_xor(s, 1);
        s += __shfl_xor(s, 2);
        s += __shfl_xor(s, 4);
        s += __shfl_xor(s, 8);
        inv[r] = 1.f / s;
    }
    #pragma unroll
    for (int ntd = 0; ntd < 4; ++ntd)
        #pragma unroll
        for (int r = 0; r < 4; ++r) {
            const int qg = q0 + fg * 4 + r;
            const size_t off = ((size_t)(b * SEQ + qg)) * D_MODEL
                             + h * DK + ntd * 16 + fr;
            ctx[off] = f2bf(oacc[ntd][r] * inv[r]);
        }
}

// ---------------------------------------------------------------------------
extern "C" void kernel_launch(void* const* d_in, const int* in_sizes, int n_in,
                              void* d_out, int out_size, void* d_ws, size_t ws_size,
                              hipStream_t stream)
{
    const float* Q  = (const float*)d_in[0];
    const float* K  = (const float*)d_in[1];
    const float* V  = (const float*)d_in[2];
    const float* Wq = (const float*)d_in[3];
    const float* bq = (const float*)d_in[4];
    const float* Wk = (const float*)d_in[5];
    const float* bk = (const float*)d_in[6];
    const float* Wv = (const float*)d_in[7];
    const float* bv = (const float*)d_in[8];
    const float* Wo = (const float*)d_in[9];
    const float* bo = (const float*)d_in[10];

    char* ws = (char*)d_ws;
    const size_t SZ_ACT = (size_t)MTOT * D_MODEL * 2;      // 8 MiB
    const size_t SZ_W   = (size_t)D_MODEL * D_MODEL * 2;   // 2 MiB
    unsigned short* Qb  = (unsigned short*)(ws);
    unsigned short* Kb  = (unsigned short*)(ws + SZ_ACT);
    unsigned short* Vb  = (unsigned short*)(ws + 2 * SZ_ACT);
    unsigned short* Wqb = (unsigned short*)(ws + 3 * SZ_ACT);
    unsigned short* Wkb = (unsigned short*)(ws + 3 * SZ_ACT + SZ_W);
    unsigned short* Wvb = (unsigned short*)(ws + 3 * SZ_ACT + 2 * SZ_W);
    unsigned short* Wob = (unsigned short*)(ws + 3 * SZ_ACT + 3 * SZ_W);
    unsigned short* qhd = (unsigned short*)(ws + 3 * SZ_ACT + 4 * SZ_W);
    unsigned short* khd = (unsigned short*)(ws + 4 * SZ_ACT + 4 * SZ_W);
    unsigned short* vTd = (unsigned short*)(ws + 5 * SZ_ACT + 4 * SZ_W);
    unsigned short* ctx = (unsigned short*)(ws + 6 * SZ_ACT + 4 * SZ_W);

    const int nAct = MTOT * D_MODEL;        // 4194304
    const int nW   = D_MODEL * D_MODEL;     // 1048576

    cast_f32_bf16<<<dim3(nAct / (256 * 8), 3), 256, 0, stream>>>(
        Q, K, V, nullptr, Qb, Kb, Vb, nullptr, nAct);
    cast_f32_bf16<<<dim3(nW / (256 * 8), 4), 256, 0, stream>>>(
        Wq, Wk, Wv, Wo, Wqb, Wkb, Wvb, Wob, nW);

    qkv_gemm<<<dim3(MTOT / 128, 24), 256, 0, stream>>>(
        Qb, Kb, Vb, Wqb, Wkb, Wvb, bq, bk, bv, qhd, khd, vTd);

    attn_fwd<<<dim3(SEQ / 64, NHEAD, BATCH), 256, 0, stream>>>(
        qhd, khd, vTd, ctx);

    oproj_gemm<<<dim3(MTOT / 128, D_MODEL / 128), 256, 0, stream>>>(
        ctx, Wob, bo, (float*)d_out);
}

// Round 4
// 249.349 us; speedup vs baseline: 1.2740x; 1.0018x over previous
//
#include <hip/hip_runtime.h>
#include <hip/hip_bf16.h>

// ---------------------------------------------------------------------------
// Fused MHA forward on MI355X (gfx950), bf16 MFMA pipeline:
//   1) cast f32->bf16 (activations, weights)
//   2) fused QKV projection GEMM (double-buffered prefetch), epilogue ->
//      head layouts; Q pre-scaled by 0.125*log2(e) (softmax fold)
//   3) flash attention: XOR-swizzled K/V LDS, gload_lds dbuf prefetch,
//      defer-max online softmax, P via round-2-verified swizzled LDS path
//      (scalar b16 writes + b128 reads), setprio around MFMA
//   4) output projection GEMM (same dbuf core), fp32 + bias epilogue
// Round-3 tr_read P path REVERTED: ds_read_b64_tr_b16 requires fixed
// 16-bf16 subtile stride (m222); the padded 88-elem layout violated it.
// ---------------------------------------------------------------------------

typedef __attribute__((ext_vector_type(8))) short short8;   // 8 x bf16 bits
typedef __attribute__((ext_vector_type(4))) float f32x4;
typedef __attribute__((ext_vector_type(4))) unsigned short us4;

static constexpr int D_MODEL = 1024;
static constexpr int NHEAD   = 16;
static constexpr int DK      = 64;
static constexpr int SEQ     = 2048;
static constexpr int BATCH   = 2;
static constexpr int MTOT    = BATCH * SEQ;   // 4096

// softmax scale folded into Q projection: 1/sqrt(64) * log2(e)
static constexpr float QSCL = 0.125f * 1.44269504088896340736f;

#define DEVINL __device__ __forceinline__

DEVINL unsigned short f2bf(float f) {
    __hip_bfloat16 h = __float2bfloat16(f);   // RNE
    return *reinterpret_cast<unsigned short*>(&h);
}

// ---------------------------------------------------------------------------
// Cast kernel: up to 4 tensors of identical length, grid.y selects.
// ---------------------------------------------------------------------------
__global__ __launch_bounds__(256) void cast_f32_bf16(
    const float* __restrict__ s0, const float* __restrict__ s1,
    const float* __restrict__ s2, const float* __restrict__ s3,
    unsigned short* __restrict__ d0, unsigned short* __restrict__ d1,
    unsigned short* __restrict__ d2, unsigned short* __restrict__ d3,
    int n)
{
    const float* s; unsigned short* d;
    switch (blockIdx.y) {
        case 0:  s = s0; d = d0; break;
        case 1:  s = s1; d = d1; break;
        case 2:  s = s2; d = d2; break;
        default: s = s3; d = d3; break;
    }
    int i = (blockIdx.x * 256 + threadIdx.x) * 8;
    if (i + 8 > n) return;
    float4 v0 = *reinterpret_cast<const float4*>(s + i);
    float4 v1 = *reinterpret_cast<const float4*>(s + i + 4);
    union { unsigned short u[8]; short8 v; } o;
    o.u[0] = f2bf(v0.x); o.u[1] = f2bf(v0.y); o.u[2] = f2bf(v0.z); o.u[3] = f2bf(v0.w);
    o.u[4] = f2bf(v1.x); o.u[5] = f2bf(v1.y); o.u[6] = f2bf(v1.z); o.u[7] = f2bf(v1.w);
    *reinterpret_cast<short8*>(d + i) = o.v;
}

// ---------------------------------------------------------------------------
// GEMM core: C[m,n] = (sum_k A[m,k]*W[n,k] + bias[n]) * oscale
// 128x128 tile, BK=32, 4 waves, 16x16x32 bf16 MFMA.
// Double-buffered LDS + prefetch-next-before-compute: one barrier per
// K-step; global_load_lds(16B) stays in flight across the MFMA cluster,
// drained by the compiler's vmcnt(0) at the barrier.
// MODE 0: out bf16, head layout  [B,H,S,DK]
// MODE 1: out bf16, vT layout    [B,H,DK,S] (8B packed stores)
// MODE 2: out f32,  row-major    [M,D_MODEL]
// ---------------------------------------------------------------------------
template<int MODE>
DEVINL void gemm_core(const unsigned short* __restrict__ A,
                      const unsigned short* __restrict__ W,
                      const float* __restrict__ bias,
                      void* __restrict__ outp,
                      int m0, int n0, float oscale,
                      unsigned short* a_lds, unsigned short* b_lds) // [2][4096]
{
    constexpr int K = 1024;
    const int tid  = threadIdx.x;
    const int wave = tid >> 6, lane = tid & 63;
    const int wrow = (wave >> 1) * 64, wcol = (wave & 1) * 64;
    const int fr = lane & 15, fg = lane >> 4;

    f32x4 acc[4][4];
    #pragma unroll
    for (int i = 0; i < 4; ++i)
        #pragma unroll
        for (int j = 0; j < 4; ++j)
            acc[i][j] = (f32x4){0.f, 0.f, 0.f, 0.f};

    const int c0 = tid, c1 = tid + 256;
    const unsigned short* gA0 = A + (size_t)(m0 + (c0 >> 2)) * K + (c0 & 3) * 8;
    const unsigned short* gA1 = A + (size_t)(m0 + (c1 >> 2)) * K + (c1 & 3) * 8;
    const unsigned short* gB0 = W + (size_t)(n0 + (c0 >> 2)) * K + (c0 & 3) * 8;
    const unsigned short* gB1 = W + (size_t)(n0 + (c1 >> 2)) * K + (c1 & 3) * 8;
    char* aLb = (char*)a_lds + wave * 1024;
    char* bLb = (char*)b_lds + wave * 1024;

    auto stage = [&](int buf, int kt) {
        const int bo = buf * 8192;
        __builtin_amdgcn_global_load_lds(gA0 + kt * 32, aLb + bo,        16, 0, 0);
        __builtin_amdgcn_global_load_lds(gA1 + kt * 32, aLb + bo + 4096, 16, 0, 0);
        __builtin_amdgcn_global_load_lds(gB0 + kt * 32, bLb + bo,        16, 0, 0);
        __builtin_amdgcn_global_load_lds(gB1 + kt * 32, bLb + bo + 4096, 16, 0, 0);
    };

    stage(0, 0);
    __syncthreads();
    int cur = 0;

    for (int kt = 0; kt < K / 32; ++kt) {
        if (kt + 1 < K / 32) stage(cur ^ 1, kt + 1);

        const unsigned short* aF = a_lds + cur * 4096 + (wrow + fr) * 32 + fg * 8;
        const unsigned short* bF = b_lds + cur * 4096 + (wcol + fr) * 32 + fg * 8;
        short8 af[4], bf[4];
        #pragma unroll
        for (int mt = 0; mt < 4; ++mt)
            af[mt] = *reinterpret_cast<const short8*>(aF + mt * 16 * 32);
        #pragma unroll
        for (int nt = 0; nt < 4; ++nt)
            bf[nt] = *reinterpret_cast<const short8*>(bF + nt * 16 * 32);
        __builtin_amdgcn_s_setprio(1);
        #pragma unroll
        for (int mt = 0; mt < 4; ++mt)
            #pragma unroll
            for (int nt = 0; nt < 4; ++nt)
                acc[mt][nt] = __builtin_amdgcn_mfma_f32_16x16x32_bf16(
                    af[mt], bf[nt], acc[mt][nt], 0, 0, 0);
        __builtin_amdgcn_s_setprio(0);

        __syncthreads();   // drains vmcnt(0): prefetch landed; reads of cur done
        cur ^= 1;
    }

    // epilogue: C/D layout col = lane&15 (=n), row = (lane>>4)*4 + r (=m)
    #pragma unroll
    for (int mt = 0; mt < 4; ++mt) {
        #pragma unroll
        for (int nt = 0; nt < 4; ++nt) {
            f32x4 v = acc[mt][nt];
            const int n = n0 + wcol + nt * 16 + fr;
            const float bi = bias[n];
            if constexpr (MODE == 2) {
                #pragma unroll
                for (int r = 0; r < 4; ++r) {
                    const int m = m0 + wrow + mt * 16 + fg * 4 + r;
                    ((float*)outp)[(size_t)m * D_MODEL + n] = (v[r] + bi) * oscale;
                }
            } else if constexpr (MODE == 0) {
                #pragma unroll
                for (int r = 0; r < 4; ++r) {
                    const int m = m0 + wrow + mt * 16 + fg * 4 + r;
                    const int b = m >> 11, s = m & 2047;
                    const int h = n >> 6,  d = n & 63;
                    ((unsigned short*)outp)[((size_t)(b * NHEAD + h) * SEQ + s) * DK + d]
                        = f2bf((v[r] + bi) * oscale);
                }
            } else {   // MODE 1: vT [B,H,DK,S], 4 consecutive s -> 8B store
                const int sbase = m0 + wrow + mt * 16 + fg * 4;
                const int b = sbase >> 11, s = sbase & 2047;
                const int h = n >> 6, d = n & 63;
                us4 pk;
                #pragma unroll
                for (int r = 0; r < 4; ++r)
                    pk[r] = f2bf((v[r] + bi) * oscale);
                *reinterpret_cast<us4*>(
                    (unsigned short*)outp
                    + ((size_t)(b * NHEAD + h) * DK + d) * SEQ + s) = pk;
            }
        }
    }
}

__global__ __launch_bounds__(256) void qkv_gemm(
    const unsigned short* __restrict__ Qb, const unsigned short* __restrict__ Kb,
    const unsigned short* __restrict__ Vb,
    const unsigned short* __restrict__ Wq, const unsigned short* __restrict__ Wk,
    const unsigned short* __restrict__ Wv,
    const float* __restrict__ bq, const float* __restrict__ bk,
    const float* __restrict__ bv,
    unsigned short* __restrict__ qh, unsigned short* __restrict__ kh,
    unsigned short* __restrict__ vT)
{
    __shared__ unsigned short a_lds[2 * 128 * 32];
    __shared__ unsigned short b_lds[2 * 128 * 32];
    const int sel = blockIdx.y >> 3;
    const int n0  = (blockIdx.y & 7) * 128;
    const int m0  = blockIdx.x * 128;
    if (sel == 0)      gemm_core<0>(Qb, Wq, bq, qh, m0, n0, QSCL, a_lds, b_lds);
    else if (sel == 1) gemm_core<0>(Kb, Wk, bk, kh, m0, n0, 1.0f, a_lds, b_lds);
    else               gemm_core<1>(Vb, Wv, bv, vT, m0, n0, 1.0f, a_lds, b_lds);
}

__global__ __launch_bounds__(256) void oproj_gemm(
    const unsigned short* __restrict__ ctx, const unsigned short* __restrict__ Wo,
    const float* __restrict__ bo, float* __restrict__ out)
{
    __shared__ unsigned short a_lds[2 * 128 * 32];
    __shared__ unsigned short b_lds[2 * 128 * 32];
    gemm_core<2>(ctx, Wo, bo, out, blockIdx.x * 128, blockIdx.y * 128, 1.0f,
                 a_lds, b_lds);
}

// ---------------------------------------------------------------------------
// Flash attention: grid (S/64, H, B), 256 threads (4 waves).
// Wave w owns q-rows [blk*64 + w*16, +16). KV tiles of 64, double-buffered.
// K tile [64 kv][64 d], V^T tile [64 d][64 kv]: XOR-swizzled rows
// (byte ^= (row&7)<<4), staged via global_load_lds w/ pre-swizzled source.
// P: wave-private [16 q][64 kv] swizzled tile, scalar b16 writes + b128
// reads (round-2-verified, zero bank conflicts measured).
// Online softmax: defer-max (THR=8 log2), per-lane partial l, end reduce.
// ---------------------------------------------------------------------------
__global__ __launch_bounds__(256) void attn_fwd(
    const unsigned short* __restrict__ qh,
    const unsigned short* __restrict__ kh,
    const unsigned short* __restrict__ vT,
    unsigned short* __restrict__ ctx)
{
    __shared__ unsigned short k_lds[2][64 * 64];   // 16 KiB
    __shared__ unsigned short v_lds[2][64 * 64];   // 16 KiB
    __shared__ unsigned short p_lds[4][16 * 64];   // 8 KiB (per-wave private)

    const int tid  = threadIdx.x;
    const int wave = tid >> 6, lane = tid & 63;
    const int fr = lane & 15, fg = lane >> 4;
    const int swz = (fr & 7) << 4;
    const int h = blockIdx.y, b = blockIdx.z;
    const int q0 = blockIdx.x * 64 + wave * 16;

    const size_t headoff = (size_t)(b * NHEAD + h) * SEQ * DK;
    const unsigned short* qbase = qh + headoff;
    const unsigned short* kbase = kh + headoff;
    const unsigned short* vbase = vT + headoff;   // [DK][SEQ]

    // Q fragments (A-frag: row q=fr, k-chunk fg*8); Q is pre-scaled by QSCL
    short8 qf[2];
    #pragma unroll
    for (int ks = 0; ks < 2; ++ks)
        qf[ks] = *reinterpret_cast<const short8*>(
            qbase + (size_t)(q0 + fr) * DK + ks * 32 + fg * 8);

    // staging: chunk c -> lds byte c*16 (linear); row=c>>3, slot=(c&7)^(row&7)
    const int c0 = tid, c1 = 256 + tid;
    const int r0 = c0 >> 3, s0i = (c0 & 7) ^ (r0 & 7);
    const int r1 = c1 >> 3, s1i = (c1 & 7) ^ (r1 & 7);
    const unsigned short* gk0 = kbase + (size_t)r0 * DK + s0i * 8;
    const unsigned short* gk1 = kbase + (size_t)r1 * DK + s1i * 8;
    const unsigned short* gv0 = vbase + (size_t)r0 * SEQ + s0i * 8;
    const unsigned short* gv1 = vbase + (size_t)r1 * SEQ + s1i * 8;

    auto stage = [&](int buf, int kv0) {
        char* kb = (char*)k_lds[buf] + wave * 1024;
        char* vb = (char*)v_lds[buf] + wave * 1024;
        __builtin_amdgcn_global_load_lds(gk0 + (size_t)kv0 * DK, kb,        16, 0, 0);
        __builtin_amdgcn_global_load_lds(gk1 + (size_t)kv0 * DK, kb + 4096, 16, 0, 0);
        __builtin_amdgcn_global_load_lds(gv0 + kv0,              vb,        16, 0, 0);
        __builtin_amdgcn_global_load_lds(gv1 + kv0,              vb + 4096, 16, 0, 0);
    };

    f32x4 oacc[4];
    #pragma unroll
    for (int i = 0; i < 4; ++i) oacc[i] = (f32x4){0.f, 0.f, 0.f, 0.f};
    float mrun[4], lpart[4];
    #pragma unroll
    for (int r = 0; r < 4; ++r) { mrun[r] = -1e30f; lpart[r] = 0.f; }

    constexpr float THR = 8.0f;

    char* pwr = (char*)p_lds[wave];
    const char* prd = (const char*)p_lds[wave] + fr * 128;

    stage(0, 0);
    __syncthreads();
    int cur = 0;

    for (int kt = 0; kt < SEQ / 64; ++kt) {
        if (kt + 1 < SEQ / 64) stage(cur ^ 1, (kt + 1) * 64);

        const char* kl = (const char*)k_lds[cur];
        const char* vl = (const char*)v_lds[cur];

        // S = Q.K^T (16q x 64kv): D row q = fg*4+r, col kv = nt*16+fr
        f32x4 sacc[4];
        #pragma unroll
        for (int i = 0; i < 4; ++i) sacc[i] = (f32x4){0.f, 0.f, 0.f, 0.f};
        __builtin_amdgcn_s_setprio(1);
        #pragma unroll
        for (int ks = 0; ks < 2; ++ks) {
            #pragma unroll
            for (int nt = 0; nt < 4; ++nt) {
                const int krow = nt * 16 + fr;   // krow&7 == fr&7
                short8 kf = *reinterpret_cast<const short8*>(
                    kl + krow * 128 + ((ks * 64 + fg * 16) ^ swz));
                sacc[nt] = __builtin_amdgcn_mfma_f32_16x16x32_bf16(
                    qf[ks], kf, sacc[nt], 0, 0, 0);
            }
        }
        __builtin_amdgcn_s_setprio(0);

        // defer-max (log2 domain, scale pre-folded into Q)
        float lmax[4];
        bool need = false;
        #pragma unroll
        for (int r = 0; r < 4; ++r) {
            lmax[r] = fmaxf(fmaxf(sacc[0][r], sacc[1][r]),
                            fmaxf(sacc[2][r], sacc[3][r]));
            need |= (lmax[r] > mrun[r] + THR);
        }
        if (__any(need)) {   // first tile + rare growth
            #pragma unroll
            for (int r = 0; r < 4; ++r) {
                float mx = fmaxf(lmax[r], mrun[r]);
                mx = fmaxf(mx, __shfl_xor(mx, 1));
                mx = fmaxf(mx, __shfl_xor(mx, 2));
                mx = fmaxf(mx, __shfl_xor(mx, 4));
                mx = fmaxf(mx, __shfl_xor(mx, 8));
                const float alpha = __builtin_amdgcn_exp2f(mrun[r] - mx);
                mrun[r] = mx;
                lpart[r] *= alpha;
                #pragma unroll
                for (int ntd = 0; ntd < 4; ++ntd)
                    oacc[ntd][r] *= alpha;
            }
        }

        // P = exp2(S - m), per-lane partial row sums
        #pragma unroll
        for (int r = 0; r < 4; ++r) {
            float rs = 0.f;
            #pragma unroll
            for (int nt = 0; nt < 4; ++nt) {
                const float p = __builtin_amdgcn_exp2f(sacc[nt][r] - mrun[r]);
                sacc[nt][r] = p;
                rs += p;
            }
            lpart[r] += rs;
        }

        // P -> wave-private swizzled LDS [16 q][64 kv] (round-2-verified)
        #pragma unroll
        for (int nt = 0; nt < 4; ++nt)
            #pragma unroll
            for (int r = 0; r < 4; ++r) {
                const int qrow = fg * 4 + r;
                *(unsigned short*)(pwr + qrow * 128
                    + ((nt * 32 + fr * 2) ^ ((qrow & 7) << 4)))
                    = f2bf(sacc[nt][r]);
            }

        // O += P.V^T : A=P rows q=fr, B=V^T rows d=fr, contract over kv
        #pragma unroll
        for (int ks = 0; ks < 2; ++ks) {
            short8 pf = *reinterpret_cast<const short8*>(
                prd + ((ks * 64 + fg * 16) ^ swz));
            __builtin_amdgcn_s_setprio(1);
            #pragma unroll
            for (int ntd = 0; ntd < 4; ++ntd) {
                const int vrow = ntd * 16 + fr;
                short8 vf = *reinterpret_cast<const short8*>(
                    vl + vrow * 128 + ((ks * 64 + fg * 16) ^ swz));
                oacc[ntd] = __builtin_amdgcn_mfma_f32_16x16x32_bf16(
                    pf, vf, oacc[ntd], 0, 0, 0);
            }
            __builtin_amdgcn_s_setprio(0);
        }

        __syncthreads();   // all waves done with buf cur; prefetch landed
        cur ^= 1;
    }

    // final: reduce per-lane l partials, normalize, store bf16 ctx
    float inv[4];
    #pragma unroll
    for (int r = 0; r < 4; ++r) {
        float s = lpart[r];
        s += __shfl_xor(s, 1);
        s += __shfl_xor(s, 2);
        s += __shfl_xor(s, 4);
        s += __shfl_xor(s, 8);
        inv[r] = 1.f / s;
    }
    #pragma unroll
    for (int ntd = 0; ntd < 4; ++ntd)
        #pragma unroll
        for (int r = 0; r < 4; ++r) {
            const int qg = q0 + fg * 4 + r;
            const size_t off = ((size_t)(b * SEQ + qg)) * D_MODEL
                             + h * DK + ntd * 16 + fr;
            ctx[off] = f2bf(oacc[ntd][r] * inv[r]);
        }
}

// ---------------------------------------------------------------------------
extern "C" void kernel_launch(void* const* d_in, const int* in_sizes, int n_in,
                              void* d_out, int out_size, void* d_ws, size_t ws_size,
                              hipStream_t stream)
{
    const float* Q  = (const float*)d_in[0];
    const float* K  = (const float*)d_in[1];
    const float* V  = (const float*)d_in[2];
    const float* Wq = (const float*)d_in[3];
    const float* bq = (const float*)d_in[4];
    const float* Wk = (const float*)d_in[5];
    const float* bk = (const float*)d_in[6];
    const float* Wv = (const float*)d_in[7];
    const float* bv = (const float*)d_in[8];
    const float* Wo = (const float*)d_in[9];
    const float* bo = (const float*)d_in[10];

    char* ws = (char*)d_ws;
    const size_t SZ_ACT = (size_t)MTOT * D_MODEL * 2;      // 8 MiB
    const size_t SZ_W   = (size_t)D_MODEL * D_MODEL * 2;   // 2 MiB
    unsigned short* Qb  = (unsigned short*)(ws);
    unsigned short* Kb  = (unsigned short*)(ws + SZ_ACT);
    unsigned short* Vb  = (unsigned short*)(ws + 2 * SZ_ACT);
    unsigned short* Wqb = (unsigned short*)(ws + 3 * SZ_ACT);
    unsigned short* Wkb = (unsigned short*)(ws + 3 * SZ_ACT + SZ_W);
    unsigned short* Wvb = (unsigned short*)(ws + 3 * SZ_ACT + 2 * SZ_W);
    unsigned short* Wob = (unsigned short*)(ws + 3 * SZ_ACT + 3 * SZ_W);
    unsigned short* qhd = (unsigned short*)(ws + 3 * SZ_ACT + 4 * SZ_W);
    unsigned short* khd = (unsigned short*)(ws + 4 * SZ_ACT + 4 * SZ_W);
    unsigned short* vTd = (unsigned short*)(ws + 5 * SZ_ACT + 4 * SZ_W);
    unsigned short* ctx = (unsigned short*)(ws + 6 * SZ_ACT + 4 * SZ_W);

    const int nAct = MTOT * D_MODEL;        // 4194304
    const int nW   = D_MODEL * D_MODEL;     // 1048576

    cast_f32_bf16<<<dim3(nAct / (256 * 8), 3), 256, 0, stream>>>(
        Q, K, V, nullptr, Qb, Kb, Vb, nullptr, nAct);
    cast_f32_bf16<<<dim3(nW / (256 * 8), 4), 256, 0, stream>>>(
        Wq, Wk, Wv, Wo, Wqb, Wkb, Wvb, Wob, nW);

    qkv_gemm<<<dim3(MTOT / 128, 24), 256, 0, stream>>>(
        Qb, Kb, Vb, Wqb, Wkb, Wvb, bq, bk, bv, qhd, khd, vTd);

    attn_fwd<<<dim3(SEQ / 64, NHEAD, BATCH), 256, 0, stream>>>(
        qhd, khd, vTd, ctx);

    oproj_gemm<<<dim3(MTOT / 128, D_MODEL / 128), 256, 0, stream>>>(
        ctx, Wob, bo, (float*)d_out);
}

// Round 7
// 245.891 us; speedup vs baseline: 1.2919x; 1.0141x over previous
//
#include <hip/hip_runtime.h>
#include <hip/hip_bf16.h>

// ---------------------------------------------------------------------------
// Fused MHA forward on MI355X (gfx950), bf16 MFMA pipeline:
//   1) cast f32->bf16 (activations, weights)
//   2) fused QKV projection GEMM (double-buffered prefetch), epilogue ->
//      head layouts; Q pre-scaled by 0.125*log2(e) (softmax fold)
//   3) flash attention, swapped-QK^T 32x32 form: S^T = mfma(K,Q) puts a
//      full q-row of P in each lane -> lane-local softmax, P fed to PV as
//      B-operand straight from registers (bfloat162 pack + shfl_xor(32)),
//      no P LDS round-trip. K/V staging identical to the r4-verified path.
//   4) output projection GEMM (same dbuf core), fp32 + bias epilogue
// ---------------------------------------------------------------------------

typedef __attribute__((ext_vector_type(8))) short short8;    // 8 x bf16 bits
typedef __attribute__((ext_vector_type(4))) float f32x4;
typedef __attribute__((ext_vector_type(16))) float f32x16;
typedef __attribute__((ext_vector_type(4))) unsigned short us4;

static constexpr int D_MODEL = 1024;
static constexpr int NHEAD   = 16;
static constexpr int DK      = 64;
static constexpr int SEQ     = 2048;
static constexpr int BATCH   = 2;
static constexpr int MTOT    = BATCH * SEQ;   // 4096

// softmax scale folded into Q projection: 1/sqrt(64) * log2(e)
static constexpr float QSCL = 0.125f * 1.44269504088896340736f;

#define DEVINL __device__ __forceinline__

DEVINL unsigned short f2bf(float f) {
    __hip_bfloat16 h = __float2bfloat16(f);   // RNE
    return *reinterpret_cast<unsigned short*>(&h);
}

DEVINL unsigned pack2bf(float lo, float hi) {
    union { __hip_bfloat162 h2; unsigned u; } c;
    float2 f; f.x = lo; f.y = hi;
    c.h2 = __float22bfloat162_rn(f);          // .x -> bits 0-15
    return c.u;
}

// ---------------------------------------------------------------------------
// Cast kernel: up to 4 tensors of identical length, grid.y selects.
// ---------------------------------------------------------------------------
__global__ __launch_bounds__(256) void cast_f32_bf16(
    const float* __restrict__ s0, const float* __restrict__ s1,
    const float* __restrict__ s2, const float* __restrict__ s3,
    unsigned short* __restrict__ d0, unsigned short* __restrict__ d1,
    unsigned short* __restrict__ d2, unsigned short* __restrict__ d3,
    int n)
{
    const float* s; unsigned short* d;
    switch (blockIdx.y) {
        case 0:  s = s0; d = d0; break;
        case 1:  s = s1; d = d1; break;
        case 2:  s = s2; d = d2; break;
        default: s = s3; d = d3; break;
    }
    int i = (blockIdx.x * 256 + threadIdx.x) * 8;
    if (i + 8 > n) return;
    float4 v0 = *reinterpret_cast<const float4*>(s + i);
    float4 v1 = *reinterpret_cast<const float4*>(s + i + 4);
    union { unsigned short u[8]; short8 v; } o;
    o.u[0] = f2bf(v0.x); o.u[1] = f2bf(v0.y); o.u[2] = f2bf(v0.z); o.u[3] = f2bf(v0.w);
    o.u[4] = f2bf(v1.x); o.u[5] = f2bf(v1.y); o.u[6] = f2bf(v1.z); o.u[7] = f2bf(v1.w);
    *reinterpret_cast<short8*>(d + i) = o.v;
}

// ---------------------------------------------------------------------------
// GEMM core (r4-verified): C[m,n] = (A.W^T + bias)*oscale
// 128x128 tile, BK=32, 4 waves, 16x16x32 bf16 MFMA, dbuf prefetch.
// ---------------------------------------------------------------------------
template<int MODE>
DEVINL void gemm_core(const unsigned short* __restrict__ A,
                      const unsigned short* __restrict__ W,
                      const float* __restrict__ bias,
                      void* __restrict__ outp,
                      int m0, int n0, float oscale,
                      unsigned short* a_lds, unsigned short* b_lds) // [2][4096]
{
    constexpr int K = 1024;
    const int tid  = threadIdx.x;
    const int wave = tid >> 6, lane = tid & 63;
    const int wrow = (wave >> 1) * 64, wcol = (wave & 1) * 64;
    const int fr = lane & 15, fg = lane >> 4;

    f32x4 acc[4][4];
    #pragma unroll
    for (int i = 0; i < 4; ++i)
        #pragma unroll
        for (int j = 0; j < 4; ++j)
            acc[i][j] = (f32x4){0.f, 0.f, 0.f, 0.f};

    const int c0 = tid, c1 = tid + 256;
    const unsigned short* gA0 = A + (size_t)(m0 + (c0 >> 2)) * K + (c0 & 3) * 8;
    const unsigned short* gA1 = A + (size_t)(m0 + (c1 >> 2)) * K + (c1 & 3) * 8;
    const unsigned short* gB0 = W + (size_t)(n0 + (c0 >> 2)) * K + (c0 & 3) * 8;
    const unsigned short* gB1 = W + (size_t)(n0 + (c1 >> 2)) * K + (c1 & 3) * 8;
    char* aLb = (char*)a_lds + wave * 1024;
    char* bLb = (char*)b_lds + wave * 1024;

    auto stage = [&](int buf, int kt) {
        const int bo = buf * 8192;
        __builtin_amdgcn_global_load_lds(gA0 + kt * 32, aLb + bo,        16, 0, 0);
        __builtin_amdgcn_global_load_lds(gA1 + kt * 32, aLb + bo + 4096, 16, 0, 0);
        __builtin_amdgcn_global_load_lds(gB0 + kt * 32, bLb + bo,        16, 0, 0);
        __builtin_amdgcn_global_load_lds(gB1 + kt * 32, bLb + bo + 4096, 16, 0, 0);
    };

    stage(0, 0);
    __syncthreads();
    int cur = 0;

    for (int kt = 0; kt < K / 32; ++kt) {
        if (kt + 1 < K / 32) stage(cur ^ 1, kt + 1);

        const unsigned short* aF = a_lds + cur * 4096 + (wrow + fr) * 32 + fg * 8;
        const unsigned short* bF = b_lds + cur * 4096 + (wcol + fr) * 32 + fg * 8;
        short8 af[4], bf[4];
        #pragma unroll
        for (int mt = 0; mt < 4; ++mt)
            af[mt] = *reinterpret_cast<const short8*>(aF + mt * 16 * 32);
        #pragma unroll
        for (int nt = 0; nt < 4; ++nt)
            bf[nt] = *reinterpret_cast<const short8*>(bF + nt * 16 * 32);
        __builtin_amdgcn_s_setprio(1);
        #pragma unroll
        for (int mt = 0; mt < 4; ++mt)
            #pragma unroll
            for (int nt = 0; nt < 4; ++nt)
                acc[mt][nt] = __builtin_amdgcn_mfma_f32_16x16x32_bf16(
                    af[mt], bf[nt], acc[mt][nt], 0, 0, 0);
        __builtin_amdgcn_s_setprio(0);

        __syncthreads();   // drains vmcnt(0): prefetch landed; reads of cur done
        cur ^= 1;
    }

    // epilogue: C/D layout col = lane&15 (=n), row = (lane>>4)*4 + r (=m)
    #pragma unroll
    for (int mt = 0; mt < 4; ++mt) {
        #pragma unroll
        for (int nt = 0; nt < 4; ++nt) {
            f32x4 v = acc[mt][nt];
            const int n = n0 + wcol + nt * 16 + fr;
            const float bi = bias[n];
            if constexpr (MODE == 2) {
                #pragma unroll
                for (int r = 0; r < 4; ++r) {
                    const int m = m0 + wrow + mt * 16 + fg * 4 + r;
                    ((float*)outp)[(size_t)m * D_MODEL + n] = (v[r] + bi) * oscale;
                }
            } else if constexpr (MODE == 0) {
                #pragma unroll
                for (int r = 0; r < 4; ++r) {
                    const int m = m0 + wrow + mt * 16 + fg * 4 + r;
                    const int b = m >> 11, s = m & 2047;
                    const int h = n >> 6,  d = n & 63;
                    ((unsigned short*)outp)[((size_t)(b * NHEAD + h) * SEQ + s) * DK + d]
                        = f2bf((v[r] + bi) * oscale);
                }
            } else {   // MODE 1: vT [B,H,DK,S], 4 consecutive s -> 8B store
                const int sbase = m0 + wrow + mt * 16 + fg * 4;
                const int b = sbase >> 11, s = sbase & 2047;
                const int h = n >> 6, d = n & 63;
                us4 pk;
                #pragma unroll
                for (int r = 0; r < 4; ++r)
                    pk[r] = f2bf((v[r] + bi) * oscale);
                *reinterpret_cast<us4*>(
                    (unsigned short*)outp
                    + ((size_t)(b * NHEAD + h) * DK + d) * SEQ + s) = pk;
            }
        }
    }
}

__global__ __launch_bounds__(256) void qkv_gemm(
    const unsigned short* __restrict__ Qb, const unsigned short* __restrict__ Kb,
    const unsigned short* __restrict__ Vb,
    const unsigned short* __restrict__ Wq, const unsigned short* __restrict__ Wk,
    const unsigned short* __restrict__ Wv,
    const float* __restrict__ bq, const float* __restrict__ bk,
    const float* __restrict__ bv,
    unsigned short* __restrict__ qh, unsigned short* __restrict__ kh,
    unsigned short* __restrict__ vT)
{
    __shared__ unsigned short a_lds[2 * 128 * 32];
    __shared__ unsigned short b_lds[2 * 128 * 32];
    const int sel = blockIdx.y >> 3;
    const int n0  = (blockIdx.y & 7) * 128;
    const int m0  = blockIdx.x * 128;
    if (sel == 0)      gemm_core<0>(Qb, Wq, bq, qh, m0, n0, QSCL, a_lds, b_lds);
    else if (sel == 1) gemm_core<0>(Kb, Wk, bk, kh, m0, n0, 1.0f, a_lds, b_lds);
    else               gemm_core<1>(Vb, Wv, bv, vT, m0, n0, 1.0f, a_lds, b_lds);
}

__global__ __launch_bounds__(256) void oproj_gemm(
    const unsigned short* __restrict__ ctx, const unsigned short* __restrict__ Wo,
    const float* __restrict__ bo, float* __restrict__ out)
{
    __shared__ unsigned short a_lds[2 * 128 * 32];
    __shared__ unsigned short b_lds[2 * 128 * 32];
    gemm_core<2>(ctx, Wo, bo, out, blockIdx.x * 128, blockIdx.y * 128, 1.0f,
                 a_lds, b_lds);
}

// ---------------------------------------------------------------------------
// Flash attention, swapped-QK^T 32x32: grid (S/128, H, B), 256 thr (4 waves).
// Wave w owns q-rows [blk*128 + w*32, +32); lane = (q = lane&31, hi = lane>>5).
// KV tiles of 64, double-buffered; K [64 kv][64 d] and V^T [64 d][64 kv] in
// XOR-swizzled LDS (byte ^= (row&7)<<4), staged via global_load_lds with
// pre-swizzled source (identical to r4-verified staging).
//
// S^T = mfma32x32x16(A=K, B=Q): D col = q (lane&31), row = kv via
// (r&3)+8*(r>>2)+4*hi [m74/m101-verified] -> lane holds its q-row's P.
// Softmax lane-local: 31-op max/sum trees + one shfl_xor(32) to merge the
// hi-halves. P -> bf16 pairs (__float22bfloat162_rn) -> PV B-operand frags
// assembled with 2 shfl_xor(32) per frag. O^T = mfma(A=V^T, B=P): lane's
// 32 outputs all share q -> l-normalize is a lane scalar.
// ---------------------------------------------------------------------------
__global__ __launch_bounds__(256) void attn_fwd(
    const unsigned short* __restrict__ qh,
    const unsigned short* __restrict__ kh,
    const unsigned short* __restrict__ vT,
    unsigned short* __restrict__ ctx)
{
    __shared__ unsigned short k_lds[2][64 * 64];   // 16 KiB
    __shared__ unsigned short v_lds[2][64 * 64];   // 16 KiB

    const int tid  = threadIdx.x;
    const int wave = tid >> 6, lane = tid & 63;
    const int q    = lane & 31, hi = lane >> 5;
    const int h = blockIdx.y, b = blockIdx.z;
    const int q0 = blockIdx.x * 128 + wave * 32;

    const size_t headoff = (size_t)(b * NHEAD + h) * SEQ * DK;
    const unsigned short* qbase = qh + headoff;
    const unsigned short* kbase = kh + headoff;
    const unsigned short* vbase = vT + headoff;   // [DK][SEQ]

    // Q as B-operand: row n=q, k-group hi*8; call c covers d = c*16..+16
    short8 qf[4];
    #pragma unroll
    for (int c = 0; c < 4; ++c)
        qf[c] = *reinterpret_cast<const short8*>(
            qbase + (size_t)(q0 + q) * DK + c * 16 + hi * 8);

    // staging (r4-verified): chunk c -> lds byte c*16; row=c>>3,
    // src slot = (c&7)^(row&7)
    const int c0 = tid, c1 = 256 + tid;
    const int r0 = c0 >> 3, s0i = (c0 & 7) ^ (r0 & 7);
    const int r1 = c1 >> 3, s1i = (c1 & 7) ^ (r1 & 7);
    const unsigned short* gk0 = kbase + (size_t)r0 * DK + s0i * 8;
    const unsigned short* gk1 = kbase + (size_t)r1 * DK + s1i * 8;
    const unsigned short* gv0 = vbase + (size_t)r0 * SEQ + s0i * 8;
    const unsigned short* gv1 = vbase + (size_t)r1 * SEQ + s1i * 8;

    auto stage = [&](int buf, int kv0) {
        char* kb = (char*)k_lds[buf] + wave * 1024;
        char* vb = (char*)v_lds[buf] + wave * 1024;
        __builtin_amdgcn_global_load_lds(gk0 + (size_t)kv0 * DK, kb,        16, 0, 0);
        __builtin_amdgcn_global_load_lds(gk1 + (size_t)kv0 * DK, kb + 4096, 16, 0, 0);
        __builtin_amdgcn_global_load_lds(gv0 + kv0,              vb,        16, 0, 0);
        __builtin_amdgcn_global_load_lds(gv1 + kv0,              vb + 4096, 16, 0, 0);
    };

    f32x16 oacc[2];
    #pragma unroll
    for (int kd = 0; kd < 2; ++kd)
        #pragma unroll
        for (int r = 0; r < 16; ++r) oacc[kd][r] = 0.f;
    float mrun = -1e30f, lpart = 0.f;
    constexpr float THR = 8.0f;

    stage(0, 0);
    __syncthreads();
    int cur = 0;

    for (int kt = 0; kt < SEQ / 64; ++kt) {
        if (kt + 1 < SEQ / 64) stage(cur ^ 1, (kt + 1) * 64);

        const char* kl = (const char*)k_lds[cur];
        const char* vl = (const char*)v_lds[cur];

        // S^T: per kv-block kb (32 kv), acc over d: 4 calls of K=16
        f32x16 sacc[2];
        #pragma unroll
        for (int kb = 0; kb < 2; ++kb)
            #pragma unroll
            for (int r = 0; r < 16; ++r) sacc[kb][r] = 0.f;

        __builtin_amdgcn_s_setprio(1);
        #pragma unroll
        for (int kb = 0; kb < 2; ++kb) {
            const int krow = kb * 32 + q;
            const int ksw  = (krow & 7) << 4;
            #pragma unroll
            for (int c = 0; c < 4; ++c) {
                short8 kf = *reinterpret_cast<const short8*>(
                    kl + krow * 128 + ((c * 32 + hi * 16) ^ ksw));
                sacc[kb] = __builtin_amdgcn_mfma_f32_32x32x16_bf16(
                    kf, qf[c], sacc[kb], 0, 0, 0);
            }
        }
        __builtin_amdgcn_s_setprio(0);

        // lane-local max over the 32 S values, merge hi-halves with one swap
        float pm = sacc[0][0];
        #pragma unroll
        for (int r = 1; r < 16; ++r) pm = fmaxf(pm, sacc[0][r]);
        #pragma unroll
        for (int r = 0; r < 16; ++r) pm = fmaxf(pm, sacc[1][r]);
        pm = fmaxf(pm, __shfl_xor(pm, 32));

        // defer-max: rescale only on first tile / rare growth
        if (__any(pm > mrun + THR)) {
            const float mx = fmaxf(pm, mrun);
            const float alpha = __builtin_amdgcn_exp2f(mrun - mx);
            mrun = mx;
            lpart *= alpha;
            #pragma unroll
            for (int kd = 0; kd < 2; ++kd)
                #pragma unroll
                for (int r = 0; r < 16; ++r) oacc[kd][r] *= alpha;
        }

        // P = exp2(S - m); lane-partial row sum, merge halves once
        float ps = 0.f;
        #pragma unroll
        for (int kb = 0; kb < 2; ++kb)
            #pragma unroll
            for (int r = 0; r < 16; ++r) {
                const float p = __builtin_amdgcn_exp2f(sacc[kb][r] - mrun);
                sacc[kb][r] = p;
                ps += p;
            }
        ps += __shfl_xor(ps, 32);
        lpart += ps;

        // pack P to bf16 pairs: w[kb][m] = bf16x2 of regs (2m, 2m+1)
        unsigned w[2][8];
        #pragma unroll
        for (int kb = 0; kb < 2; ++kb)
            #pragma unroll
            for (int m = 0; m < 8; ++m)
                w[kb][m] = pack2bf(sacc[kb][2 * m], sacc[kb][2 * m + 1]);

        // O^T += V^T . P : per (kb,kc) assemble B-frag from registers,
        // per kd read V^T A-frag and mfma.
        #pragma unroll
        for (int kb = 0; kb < 2; ++kb) {
            #pragma unroll
            for (int kc = 0; kc < 2; ++kc) {
                // own regs = block bo=2kc+hi; supply partner's block bx=2kc+(hi^1)
                const unsigned o0 = hi ? w[kb][4 * kc + 2] : w[kb][4 * kc + 0];
                const unsigned o1 = hi ? w[kb][4 * kc + 3] : w[kb][4 * kc + 1];
                const unsigned sp0 = hi ? w[kb][4 * kc + 0] : w[kb][4 * kc + 2];
                const unsigned sp1 = hi ? w[kb][4 * kc + 1] : w[kb][4 * kc + 3];
                const unsigned e0 = (unsigned)__shfl_xor((int)sp0, 32);
                const unsigned e1 = (unsigned)__shfl_xor((int)sp1, 32);
                union { unsigned u[4]; short8 v; } pf;
                pf.u[0] = hi ? e0 : o0;   // k elems j=0..3 come from hi=0 half
                pf.u[1] = hi ? e1 : o1;
                pf.u[2] = hi ? o0 : e0;   // j=4..7 from hi=1 half
                pf.u[3] = hi ? o1 : e1;

                __builtin_amdgcn_s_setprio(1);
                #pragma unroll
                for (int kd = 0; kd < 2; ++kd) {
                    const int vrow = kd * 32 + q;
                    const int slot = kb * 4 + kc * 2 + hi;   // 16B col chunk
                    short8 vf = *reinterpret_cast<const short8*>(
                        vl + vrow * 128 + ((slot * 16) ^ ((vrow & 7) << 4)));
                    oacc[kd] = __builtin_amdgcn_mfma_f32_32x32x16_bf16(
                        vf, pf.v, oacc[kd], 0, 0, 0);
                }
                __builtin_amdgcn_s_setprio(0);
            }
        }

        __syncthreads();   // all waves done with buf cur; prefetch landed
        cur ^= 1;
    }

    // finalize: lane-scalar normalize; store 4-elem bf16 runs (8B stores)
    const float inv = 1.f / lpart;
    unsigned short* crow = ctx + ((size_t)(b * SEQ + q0 + q)) * D_MODEL + h * DK;
    #pragma unroll
    for (int kd = 0; kd < 2; ++kd)
        #pragma unroll
        for (int rr = 0; rr < 4; ++rr) {
            us4 pk;
            #pragma unroll
            for (int e = 0; e < 4; ++e)
                pk[e] = f2bf(oacc[kd][rr * 4 + e] * inv);
            // D row = (r&3)+8*(r>>2)+4*hi -> d = kd*32 + rr*8 + hi*4 + e
            *reinterpret_cast<us4*>(crow + kd * 32 + rr * 8 + hi * 4) = pk;
        }
}

// ---------------------------------------------------------------------------
extern "C" void kernel_launch(void* const* d_in, const int* in_sizes, int n_in,
                              void* d_out, int out_size, void* d_ws, size_t ws_size,
                              hipStream_t stream)
{
    const float* Q  = (const float*)d_in[0];
    const float* K  = (const float*)d_in[1];
    const float* V  = (const float*)d_in[2];
    const float* Wq = (const float*)d_in[3];
    const float* bq = (const float*)d_in[4];
    const float* Wk = (const float*)d_in[5];
    const float* bk = (const float*)d_in[6];
    const float* Wv = (const float*)d_in[7];
    const float* bv = (const float*)d_in[8];
    const float* Wo = (const float*)d_in[9];
    const float* bo = (const float*)d_in[10];

    char* ws = (char*)d_ws;
    const size_t SZ_ACT = (size_t)MTOT * D_MODEL * 2;      // 8 MiB
    const size_t SZ_W   = (size_t)D_MODEL * D_MODEL * 2;   // 2 MiB
    unsigned short* Qb  = (unsigned short*)(ws);
    unsigned short* Kb  = (unsigned short*)(ws + SZ_ACT);
    unsigned short* Vb  = (unsigned short*)(ws + 2 * SZ_ACT);
    unsigned short* Wqb = (unsigned short*)(ws + 3 * SZ_ACT);
    unsigned short* Wkb = (unsigned short*)(ws + 3 * SZ_ACT + SZ_W);
    unsigned short* Wvb = (unsigned short*)(ws + 3 * SZ_ACT + 2 * SZ_W);
    unsigned short* Wob = (unsigned short*)(ws + 3 * SZ_ACT + 3 * SZ_W);
    unsigned short* qhd = (unsigned short*)(ws + 3 * SZ_ACT + 4 * SZ_W);
    unsigned short* khd = (unsigned short*)(ws + 4 * SZ_ACT + 4 * SZ_W);
    unsigned short* vTd = (unsigned short*)(ws + 5 * SZ_ACT + 4 * SZ_W);
    unsigned short* ctx = (unsigned short*)(ws + 6 * SZ_ACT + 4 * SZ_W);

    const int nAct = MTOT * D_MODEL;        // 4194304
    const int nW   = D_MODEL * D_MODEL;     // 1048576

    cast_f32_bf16<<<dim3(nAct / (256 * 8), 3), 256, 0, stream>>>(
        Q, K, V, nullptr, Qb, Kb, Vb, nullptr, nAct);
    cast_f32_bf16<<<dim3(nW / (256 * 8), 4), 256, 0, stream>>>(
        Wq, Wk, Wv, Wo, Wqb, Wkb, Wvb, Wob, nW);

    qkv_gemm<<<dim3(MTOT / 128, 24), 256, 0, stream>>>(
        Qb, Kb, Vb, Wqb, Wkb, Wvb, bq, bk, bv, qhd, khd, vTd);

    attn_fwd<<<dim3(SEQ / 128, NHEAD, BATCH), 256, 0, stream>>>(
        qhd, khd, vTd, ctx);

    oproj_gemm<<<dim3(MTOT / 128, D_MODEL / 128), 256, 0, stream>>>(
        ctx, Wob, bo, (float*)d_out);
}